// Round 1
// baseline (195.274 us; speedup 1.0000x reference)
//
#include <hip/hip_runtime.h>

#define SMOOTH 1e-5f

// Workspace layout: ws[scale][img][5] floats = {C, S, inter, z_sum, p_sum}
// scale in [0,3), img = b*4+n in [0,32)

__device__ __forceinline__ float wave_reduce(float v) {
#pragma unroll
    for (int off = 32; off; off >>= 1) v += __shfl_down(v, off, 64);
    return v;
}

// Block decode:
//   scale0: 64 chunks/image * 32 images = 2048 blocks (chunk = 4096 px)
//   scale1: 16 chunks/image * 32 images =  512 blocks
//   scale2:  4 chunks/image * 32 images =  128 blocks
//   total 2688 blocks, 256 threads, 16 px/thread (4x float4)
__global__ __launch_bounds__(256) void bdou_reduce(
    const float* __restrict__ l0, const float* __restrict__ l1,
    const float* __restrict__ l2, const int* __restrict__ tgt,
    float* __restrict__ ws)
{
    int blk = blockIdx.x;
    int scale, img, chunk;
    if (blk < 2048)      { scale = 0; img = blk >> 6; chunk = blk & 63; }
    else if (blk < 2560) { int b = blk - 2048; scale = 1; img = b >> 4; chunk = b & 15; }
    else                 { int b = blk - 2560; scale = 2; img = b >> 2; chunk = b & 3; }

    const float* logits = (scale == 0) ? l0 : (scale == 1 ? l1 : l2);
    const int hshift = 9 - scale;          // log2 of downsampled h (== w)
    const int h      = 1 << hshift;
    const int stride = 1 << scale;         // nearest-ds stride into full-res targets
    const int P      = h * h;
    const int*   timg = tgt    + (size_t)img * (512 * 512);
    const float* limg = logits + (size_t)img * P;

    float accC = 0.f, accS = 0.f, accI = 0.f, accZ = 0.f, accP = 0.f;
    const int tid   = threadIdx.x;
    const int start = chunk * 4096;

#pragma unroll
    for (int it = 0; it < 4; ++it) {
        int p0 = start + it * 1024 + tid * 4;
        float4 lg = *reinterpret_cast<const float4*>(limg + p0);
        float raw[4] = {lg.x, lg.y, lg.z, lg.w};
#pragma unroll
        for (int j = 0; j < 4; ++j) {
            int p = p0 + j;
            int y = p >> hshift;
            int x = p & (h - 1);
            float prob = 1.f / (1.f + __expf(-raw[j]));
            accP += prob;
            accZ += prob * prob;
            int trow = y * stride, tcol = x * stride;
            int t = timg[trow * 512 + tcol];
            if (t) {
                accS += 1.f;
                accI += prob;
                // cross-conv == 5 iff all 4-neighbors (downsampled grid,
                // zero padding) are fg; else boundary pixel
                int sum = 1;
                if (y > 0)     sum += timg[(trow - stride) * 512 + tcol];
                if (y < h - 1) sum += timg[(trow + stride) * 512 + tcol];
                if (x > 0)     sum += timg[trow * 512 + tcol - stride];
                if (x < h - 1) sum += timg[trow * 512 + tcol + stride];
                if (sum != 5)  accC += 1.f;
            }
        }
    }

    float vals[5] = {accC, accS, accI, accZ, accP};
    __shared__ float red[4][5];
#pragma unroll
    for (int k = 0; k < 5; ++k) vals[k] = wave_reduce(vals[k]);
    int wave = tid >> 6, lane = tid & 63;
    if (lane == 0) {
#pragma unroll
        for (int k = 0; k < 5; ++k) red[wave][k] = vals[k];
    }
    __syncthreads();
    if (tid < 5) {
        float s = red[0][tid] + red[1][tid] + red[2][tid] + red[3][tid];
        atomicAdd(&ws[(scale * 32 + img) * 5 + tid], s);
    }
}

__global__ void bdou_final(const float* __restrict__ ws,
                           const float* __restrict__ valid_mask,
                           float* __restrict__ out)
{
    if (threadIdx.x != 0 || blockIdx.x != 0) return;
    float valid[32];
    float cnt = 0.f;
    for (int i = 0; i < 32; ++i) {
        valid[i] = (valid_mask[i] >= 0.5f) ? 1.f : 0.f;
        cnt += valid[i];
    }
    const float wts[3] = {1.f / 1.75f, 0.5f / 1.75f, 0.25f / 1.75f};
    const float pix[3] = {262144.f, 65536.f, 16384.f};
    float loss = 0.f;
    for (int s = 0; s < 3; ++s) {
        float acc = 0.f;
        for (int i = 0; i < 32; ++i) {
            const float* w = ws + (s * 32 + i) * 5;
            float C = w[0], S = w[1], I = w[2], Z = w[3], Ps = w[4];
            float alpha = 2.f * (1.f - (C + SMOOTH) / (S + SMOOTH)) - 1.f;
            alpha = fminf(alpha, 0.8f);
            float dou = (Z + S - 2.f * I + SMOOTH) /
                        (Z + S - (1.f + alpha) * I + SMOOTH);
            float per = (S > 0.f) ? dou : (Ps / pix[s]);
            acc += per * valid[i];
        }
        loss += wts[s] * ((cnt > 0.f) ? acc / cnt : 0.f);
    }
    out[0] = loss;
}

extern "C" void kernel_launch(void* const* d_in, const int* in_sizes, int n_in,
                              void* d_out, int out_size, void* d_ws, size_t ws_size,
                              hipStream_t stream) {
    const float* l0 = (const float*)d_in[0];
    const float* l1 = (const float*)d_in[1];
    const float* l2 = (const float*)d_in[2];
    const int*   tg = (const int*)d_in[3];
    const float* vm = (const float*)d_in[4];
    float* ws = (float*)d_ws;

    hipMemsetAsync(ws, 0, 3 * 32 * 5 * sizeof(float), stream);
    bdou_reduce<<<2688, 256, 0, stream>>>(l0, l1, l2, tg, ws);
    bdou_final<<<1, 64, 0, stream>>>(ws, vm, (float*)d_out);
}

// Round 2
// 130.339 us; speedup vs baseline: 1.4982x; 1.4982x over previous
//
#include <hip/hip_runtime.h>

#define SMOOTH 1e-5f

// Workspace: ws[scale][img][5] floats = {C, S, inter, z_sum, p_sum}

__device__ __forceinline__ float wave_reduce(float v) {
#pragma unroll
    for (int off = 32; off; off >>= 1) v += __shfl_down(v, off, 64);
    return v;
}

__device__ __forceinline__ float sigmoidf(float x) {
    return 1.f / (1.f + __expf(-x));
}

__device__ __forceinline__ void accum_px(const float pr[4], const int t[4],
    const int u[4], const int d[4], const int l[4], const int r[4],
    int& cC, int& cS, float& aI, float& aZ, float& aP)
{
#pragma unroll
    for (int j = 0; j < 4; ++j) {
        cS += t[j];
        cC += t[j] & ~(u[j] & d[j] & l[j] & r[j]);   // t - interior (t,u,d,l,r in {0,1})
        aI += pr[j] * (float)t[j];
        aZ += pr[j] * pr[j];
        aP += pr[j];
    }
}

// Block decode:
//   scale0: 64 chunks/image * 32 images = 2048 blocks (chunk = 4096 px)
//   scale1: 16 chunks/image * 32 images =  512 blocks
//   scale2:  4 chunks/image * 32 images =  128 blocks
// 256 threads, 16 px/thread (4 iterations x 4 consecutive px).
__global__ __launch_bounds__(256) void bdou_reduce(
    const float* __restrict__ l0, const float* __restrict__ l1,
    const float* __restrict__ l2, const int* __restrict__ tgt,
    float* __restrict__ ws)
{
    int blk = blockIdx.x;
    int scale, img, chunk;
    if (blk < 2048)      { scale = 0; img = blk >> 6; chunk = blk & 63; }
    else if (blk < 2560) { int b = blk - 2048; scale = 1; img = b >> 4; chunk = b & 15; }
    else                 { int b = blk - 2560; scale = 2; img = b >> 2; chunk = b & 3; }

    const int* __restrict__ timg = tgt + (size_t)img * (512 * 512);
    const int tid  = threadIdx.x;
    const int base = chunk * 4096 + tid * 4;

    int   cC = 0, cS = 0;
    float aI = 0.f, aZ = 0.f, aP = 0.f;

    if (scale == 0) {
        const float* __restrict__ limg = l0 + (size_t)img * (512 * 512);
#pragma unroll
        for (int it = 0; it < 4; ++it) {
            int p0 = base + it * 1024;
            int y = p0 >> 9, x = p0 & 511;
            float4 lg = *reinterpret_cast<const float4*>(limg + p0);
            const int* row = timg + p0;                 // full-res == ds grid
            int upo = (y > 0)   ? -512 : 0;
            int dno = (y < 511) ?  512 : 0;
            int lfo = (x > 0)   ?   -1 : 0;
            int rto = (x < 508) ?    4 : 0;
            int4 tc = *reinterpret_cast<const int4*>(row);
            int4 uv = *reinterpret_cast<const int4*>(row + upo);
            int4 dv = *reinterpret_cast<const int4*>(row + dno);
            int lfv = row[lfo];
            int rtv = row[rto];
            int t[4] = {tc.x, tc.y, tc.z, tc.w};
            int u[4], d[4];
            if (y > 0)   { u[0]=uv.x; u[1]=uv.y; u[2]=uv.z; u[3]=uv.w; }
            else         { u[0]=u[1]=u[2]=u[3]=0; }
            if (y < 511) { d[0]=dv.x; d[1]=dv.y; d[2]=dv.z; d[3]=dv.w; }
            else         { d[0]=d[1]=d[2]=d[3]=0; }
            int lf = (x > 0)   ? lfv : 0;
            int rt = (x < 508) ? rtv : 0;
            int l[4] = {lf, t[0], t[1], t[2]};
            int r[4] = {t[1], t[2], t[3], rt};
            float pr[4] = {sigmoidf(lg.x), sigmoidf(lg.y), sigmoidf(lg.z), sigmoidf(lg.w)};
            accum_px(pr, t, u, d, l, r, cC, cS, aI, aZ, aP);
        }
    } else if (scale == 1) {
        const float* __restrict__ limg = l1 + (size_t)img * (256 * 256);
#pragma unroll
        for (int it = 0; it < 4; ++it) {
            int p0 = base + it * 1024;
            int y = p0 >> 8, x = p0 & 255;              // ds coords
            float4 lg = *reinterpret_cast<const float4*>(limg + p0);
            const int* row = timg + (y * 2) * 512 + x * 2;
            int upo = (y > 0)   ? -1024 : 0;            // 2 full-res rows
            int dno = (y < 255) ?  1024 : 0;
            int lfo = (x > 0)   ?    -2 : 0;
            int rto = (x < 252) ?     8 : 0;
            int4 a  = *reinterpret_cast<const int4*>(row);
            int4 b  = *reinterpret_cast<const int4*>(row + 4);
            int4 ua = *reinterpret_cast<const int4*>(row + upo);
            int4 ub = *reinterpret_cast<const int4*>(row + upo + 4);
            int4 da = *reinterpret_cast<const int4*>(row + dno);
            int4 db = *reinterpret_cast<const int4*>(row + dno + 4);
            int lfv = row[lfo];
            int rtv = row[rto];
            int t[4] = {a.x, a.z, b.x, b.z};
            int u[4], d[4];
            if (y > 0)   { u[0]=ua.x; u[1]=ua.z; u[2]=ub.x; u[3]=ub.z; }
            else         { u[0]=u[1]=u[2]=u[3]=0; }
            if (y < 255) { d[0]=da.x; d[1]=da.z; d[2]=db.x; d[3]=db.z; }
            else         { d[0]=d[1]=d[2]=d[3]=0; }
            int lf = (x > 0)   ? lfv : 0;
            int rt = (x < 252) ? rtv : 0;
            int l[4] = {lf, t[0], t[1], t[2]};
            int r[4] = {t[1], t[2], t[3], rt};
            float pr[4] = {sigmoidf(lg.x), sigmoidf(lg.y), sigmoidf(lg.z), sigmoidf(lg.w)};
            accum_px(pr, t, u, d, l, r, cC, cS, aI, aZ, aP);
        }
    } else {
        const float* __restrict__ limg = l2 + (size_t)img * (128 * 128);
#pragma unroll
        for (int it = 0; it < 4; ++it) {
            int p0 = base + it * 1024;
            int y = p0 >> 7, x = p0 & 127;
            float4 lg = *reinterpret_cast<const float4*>(limg + p0);
            const int* row = timg + (y * 4) * 512 + x * 4;
            int upo = (y > 0)   ? -2048 : 0;            // 4 full-res rows
            int dno = (y < 127) ?  2048 : 0;
            int lfo = (x > 0)   ?    -4 : 0;
            int rto = (x < 124) ?    16 : 0;
            int tv[4] = {row[0], row[4], row[8], row[12]};
            int uv[4] = {row[upo], row[upo+4], row[upo+8], row[upo+12]};
            int dv[4] = {row[dno], row[dno+4], row[dno+8], row[dno+12]};
            int lfv = row[lfo];
            int rtv = row[rto];
            int t[4] = {tv[0], tv[1], tv[2], tv[3]};
            int u[4], d[4];
            if (y > 0)   { u[0]=uv[0]; u[1]=uv[1]; u[2]=uv[2]; u[3]=uv[3]; }
            else         { u[0]=u[1]=u[2]=u[3]=0; }
            if (y < 127) { d[0]=dv[0]; d[1]=dv[1]; d[2]=dv[2]; d[3]=dv[3]; }
            else         { d[0]=d[1]=d[2]=d[3]=0; }
            int lf = (x > 0)   ? lfv : 0;
            int rt = (x < 124) ? rtv : 0;
            int l[4] = {lf, t[0], t[1], t[2]};
            int r[4] = {t[1], t[2], t[3], rt};
            float pr[4] = {sigmoidf(lg.x), sigmoidf(lg.y), sigmoidf(lg.z), sigmoidf(lg.w)};
            accum_px(pr, t, u, d, l, r, cC, cS, aI, aZ, aP);
        }
    }

    float vals[5] = {(float)cC, (float)cS, aI, aZ, aP};
    __shared__ float red[4][5];
#pragma unroll
    for (int k = 0; k < 5; ++k) vals[k] = wave_reduce(vals[k]);
    int wave = tid >> 6, lane = tid & 63;
    if (lane == 0) {
#pragma unroll
        for (int k = 0; k < 5; ++k) red[wave][k] = vals[k];
    }
    __syncthreads();
    if (tid < 5) {
        float s = red[0][tid] + red[1][tid] + red[2][tid] + red[3][tid];
        atomicAdd(&ws[(scale * 32 + img) * 5 + tid], s);
    }
}

// 128 threads: tid<96 -> one (scale,img) pair each; wave+LDS reduce.
__global__ void bdou_final(const float* __restrict__ ws,
                           const float* __restrict__ valid_mask,
                           float* __restrict__ out)
{
    int tid = threadIdx.x;
    float contrib = 0.f, cpart = 0.f;
    if (tid < 96) {
        int s = tid >> 5, i = tid & 31;
        const float* w = ws + tid * 5;
        float C = w[0], S = w[1], I = w[2], Z = w[3], P = w[4];
        float valid = (valid_mask[i] >= 0.5f) ? 1.f : 0.f;
        float alpha = fminf(2.f * (1.f - (C + SMOOTH) / (S + SMOOTH)) - 1.f, 0.8f);
        float dou = (Z + S - 2.f * I + SMOOTH) /
                    (Z + S - (1.f + alpha) * I + SMOOTH);
        const float wts[3]  = {4.f / 7.f, 2.f / 7.f, 1.f / 7.f};
        const float pixc[3] = {262144.f, 65536.f, 16384.f};
        float per = (S > 0.f) ? dou : (P / pixc[s]);
        contrib = wts[s] * per * valid;
        if (tid < 32) cpart = valid;
    }
    contrib = wave_reduce(contrib);
    cpart   = wave_reduce(cpart);
    __shared__ float sm[2][2];
    int wv = tid >> 6, ln = tid & 63;
    if (ln == 0) { sm[wv][0] = contrib; sm[wv][1] = cpart; }
    __syncthreads();
    if (tid == 0) {
        float tot = sm[0][0] + sm[1][0];
        float cnt = sm[0][1] + sm[1][1];
        out[0] = (cnt > 0.f) ? tot / cnt : 0.f;
    }
}

extern "C" void kernel_launch(void* const* d_in, const int* in_sizes, int n_in,
                              void* d_out, int out_size, void* d_ws, size_t ws_size,
                              hipStream_t stream) {
    const float* l0 = (const float*)d_in[0];
    const float* l1 = (const float*)d_in[1];
    const float* l2 = (const float*)d_in[2];
    const int*   tg = (const int*)d_in[3];
    const float* vm = (const float*)d_in[4];
    float* ws = (float*)d_ws;

    hipMemsetAsync(ws, 0, 3 * 32 * 5 * sizeof(float), stream);
    bdou_reduce<<<2688, 256, 0, stream>>>(l0, l1, l2, tg, ws);
    bdou_final<<<1, 128, 0, stream>>>(ws, vm, (float*)d_out);
}

// Round 3
// 117.476 us; speedup vs baseline: 1.6622x; 1.1095x over previous
//
#include <hip/hip_runtime.h>

#define SMOOTH 1e-5f

// ws[scale][img][5] = {C, S, inter, z_sum, p_sum}

__device__ __forceinline__ float wave_reduce(float v) {
#pragma unroll
    for (int off = 32; off; off >>= 1) v += __shfl_down(v, off, 64);
    return v;
}

__device__ __forceinline__ float sigmoidf(float x) {
    return 1.f / (1.f + __expf(-x));
}

// 2048 blocks = 32 images x 64 tiles (8x8 tiles of 64x64 full-res px).
// XCD swizzle: img = blk%8 + 8*(blk/512) so one image's tiles stay on one XCD.
// Each block: stage 72x72 target halo tile (halo=4) into LDS as bytes, then
// compute boundary stencils for all 3 scales from LDS + stream logits.
__global__ __launch_bounds__(256) void bdou_fused(
    const float* __restrict__ l0, const float* __restrict__ l1,
    const float* __restrict__ l2, const int* __restrict__ tgt,
    float* __restrict__ ws)
{
    __shared__ unsigned Tw[72 * 20];          // 72 rows x 80 bytes (cols 0..71 used)
    __shared__ float red[4][15];

    const int blk  = blockIdx.x;
    const int img  = (blk & 7) + 8 * (blk >> 9);
    const int tile = (blk >> 3) & 63;
    const int ty0  = (tile >> 3) * 64;
    const int tx0  = (tile & 7) * 64;
    const int tid  = threadIdx.x;

    const int* __restrict__ timg = tgt + (size_t)img * (512 * 512);

    // ---- stage target halo tile: 72 rows x 18 int4 = 1296 jobs ----
    for (int j = tid; j < 1296; j += 256) {
        int r = j / 18, c = j - r * 18;
        int gy = ty0 - 4 + r;
        int gx = tx0 - 4 + c * 4;
        unsigned w = 0;
        if ((unsigned)gy < 512u && (unsigned)gx < 512u) {  // gx=-4 / 512 fully OOB
            int4 v = *reinterpret_cast<const int4*>(timg + (size_t)gy * 512 + gx);
            w = (v.x != 0 ? 1u : 0) | (v.y != 0 ? 1u << 8 : 0) |
                (v.z != 0 ? 1u << 16 : 0) | (v.w != 0 ? 1u << 24 : 0);
        }
        Tw[r * 20 + c] = w;
    }
    __syncthreads();

    int   cC0 = 0, cS0 = 0, cC1 = 0, cS1 = 0, cC2 = 0, cS2 = 0;
    float aI0 = 0.f, aZ0 = 0.f, aP0 = 0.f;
    float aI1 = 0.f, aZ1 = 0.f, aP1 = 0.f;
    float aI2 = 0.f, aZ2 = 0.f, aP2 = 0.f;

    // ---- scale 0: 64x64 px, 16 px/thread ----
    {
        const float* __restrict__ l0img = l0 + (size_t)img * (512 * 512);
#pragma unroll
        for (int it = 0; it < 4; ++it) {
            int p  = tid * 4 + it * 1024;
            int ly = p >> 6, lx = p & 63;
            float4 lg = *reinterpret_cast<const float4*>(
                l0img + (size_t)(ty0 + ly) * 512 + tx0 + lx);
            int wb = lx >> 2;
            unsigned cw = Tw[(ly + 4) * 20 + wb + 1];
            unsigned lw = Tw[(ly + 4) * 20 + wb];
            unsigned rw = Tw[(ly + 4) * 20 + wb + 2];
            unsigned uw = Tw[(ly + 3) * 20 + wb + 1];
            unsigned dw = Tw[(ly + 5) * 20 + wb + 1];
            float pr[4] = {sigmoidf(lg.x), sigmoidf(lg.y), sigmoidf(lg.z), sigmoidf(lg.w)};
#pragma unroll
            for (int j = 0; j < 4; ++j) {
                unsigned t = (cw >> (8 * j)) & 1u;
                unsigned u = (uw >> (8 * j)) & 1u;
                unsigned d = (dw >> (8 * j)) & 1u;
                unsigned lf = (j == 0) ? (lw >> 24) & 1u : (cw >> (8 * (j - 1))) & 1u;
                unsigned rt = (j == 3) ? rw & 1u : (cw >> (8 * (j + 1))) & 1u;
                cS0 += (int)t;
                cC0 += (int)(t & ~(u & d & lf & rt));
                aI0 += pr[j] * (float)t;
                aZ0 += pr[j] * pr[j];
                aP0 += pr[j];
            }
        }
    }

    // ---- scale 1: 32x32 ds px in this tile, 4 px/thread ----
    {
        int dY = tid >> 3, dXb = (tid & 7) * 4;       // ds row, first ds col
        int fy = dY * 2, fx = (tid & 7) * 8;          // full-res local coords
        float4 lg = *reinterpret_cast<const float4*>(
            l1 + (size_t)img * 65536 + (size_t)(ty0 / 2 + dY) * 256 + tx0 / 2 + dXb);
        int rb = (fy + 4) * 20 + (fx >> 2);
        unsigned cwv[4] = {Tw[rb], Tw[rb + 1], Tw[rb + 2], Tw[rb + 3]};
        unsigned uwv[2] = {Tw[rb - 40 + 1], Tw[rb - 40 + 2]};
        unsigned dwv[2] = {Tw[rb + 40 + 1], Tw[rb + 40 + 2]};
        float pr[4] = {sigmoidf(lg.x), sigmoidf(lg.y), sigmoidf(lg.z), sigmoidf(lg.w)};
#pragma unroll
        for (int j = 0; j < 4; ++j) {
            // halfword index within the 4-word window: center=2+j, left=1+j, right=3+j
            unsigned t  = (cwv[(2 + j) >> 1] >> (16 * ((2 + j) & 1))) & 1u;
            unsigned lf = (cwv[(1 + j) >> 1] >> (16 * ((1 + j) & 1))) & 1u;
            unsigned rt = (cwv[(3 + j) >> 1] >> (16 * ((3 + j) & 1))) & 1u;
            unsigned u  = (uwv[((2 + j) >> 1) - 1] >> (16 * ((2 + j) & 1))) & 1u;
            unsigned d  = (dwv[((2 + j) >> 1) - 1] >> (16 * ((2 + j) & 1))) & 1u;
            cS1 += (int)t;
            cC1 += (int)(t & ~(u & d & lf & rt));
            aI1 += pr[j] * (float)t;
            aZ1 += pr[j] * pr[j];
            aP1 += pr[j];
        }
    }

    // ---- scale 2: 16x16 ds px in this tile, 1 px/thread ----
    {
        int dY = tid >> 4, dX = tid & 15;
        int fy = dY * 4, fx = dX * 4;
        const unsigned char* Tb = (const unsigned char*)Tw;
        int rc = (fy + 4) * 80 + fx + 4;
        unsigned t  = Tb[rc];
        unsigned u  = Tb[rc - 4 * 80];
        unsigned d  = Tb[rc + 4 * 80];
        unsigned lf = Tb[rc - 4];
        unsigned rt = Tb[rc + 4];
        float lg = l2[(size_t)img * 16384 + (size_t)(ty0 / 4 + dY) * 128 + tx0 / 4 + dX];
        float pr = sigmoidf(lg);
        cS2 += (int)t;
        cC2 += (int)(t & ~(u & d & lf & rt));
        aI2 += pr * (float)t;
        aZ2 += pr * pr;
        aP2 += pr;
    }

    // ---- block reduce 15 partials, atomic into ws ----
    float vals[15] = {(float)cC0, (float)cS0, aI0, aZ0, aP0,
                      (float)cC1, (float)cS1, aI1, aZ1, aP1,
                      (float)cC2, (float)cS2, aI2, aZ2, aP2};
#pragma unroll
    for (int k = 0; k < 15; ++k) vals[k] = wave_reduce(vals[k]);
    int wave = tid >> 6, lane = tid & 63;
    if (lane == 0) {
#pragma unroll
        for (int k = 0; k < 15; ++k) red[wave][k] = vals[k];
    }
    __syncthreads();
    if (tid < 15) {
        float s = red[0][tid] + red[1][tid] + red[2][tid] + red[3][tid];
        int sc = tid / 5, k = tid - sc * 5;
        atomicAdd(&ws[(sc * 32 + img) * 5 + k], s);
    }
}

// 128 threads: tid<96 -> one (scale,img) pair each; wave+LDS reduce.
__global__ void bdou_final(const float* __restrict__ ws,
                           const float* __restrict__ valid_mask,
                           float* __restrict__ out)
{
    int tid = threadIdx.x;
    float contrib = 0.f, cpart = 0.f;
    if (tid < 96) {
        int s = tid >> 5, i = tid & 31;
        const float* w = ws + tid * 5;
        float C = w[0], S = w[1], I = w[2], Z = w[3], P = w[4];
        float valid = (valid_mask[i] >= 0.5f) ? 1.f : 0.f;
        float alpha = fminf(2.f * (1.f - (C + SMOOTH) / (S + SMOOTH)) - 1.f, 0.8f);
        float dou = (Z + S - 2.f * I + SMOOTH) /
                    (Z + S - (1.f + alpha) * I + SMOOTH);
        const float wts[3]  = {4.f / 7.f, 2.f / 7.f, 1.f / 7.f};
        const float pixc[3] = {262144.f, 65536.f, 16384.f};
        float per = (S > 0.f) ? dou : (P / pixc[s]);
        contrib = wts[s] * per * valid;
        if (tid < 32) cpart = valid;
    }
    contrib = wave_reduce(contrib);
    cpart   = wave_reduce(cpart);
    __shared__ float sm[2][2];
    int wv = tid >> 6, ln = tid & 63;
    if (ln == 0) { sm[wv][0] = contrib; sm[wv][1] = cpart; }
    __syncthreads();
    if (tid == 0) {
        float tot = sm[0][0] + sm[1][0];
        float cnt = sm[0][1] + sm[1][1];
        out[0] = (cnt > 0.f) ? tot / cnt : 0.f;
    }
}

extern "C" void kernel_launch(void* const* d_in, const int* in_sizes, int n_in,
                              void* d_out, int out_size, void* d_ws, size_t ws_size,
                              hipStream_t stream) {
    const float* l0 = (const float*)d_in[0];
    const float* l1 = (const float*)d_in[1];
    const float* l2 = (const float*)d_in[2];
    const int*   tg = (const int*)d_in[3];
    const float* vm = (const float*)d_in[4];
    float* ws = (float*)d_ws;

    hipMemsetAsync(ws, 0, 3 * 32 * 5 * sizeof(float), stream);
    bdou_fused<<<2048, 256, 0, stream>>>(l0, l1, l2, tg, ws);
    bdou_final<<<1, 128, 0, stream>>>(ws, vm, (float*)d_out);
}